// Round 9
// baseline (104.849 us; speedup 1.0000x reference)
//
#include <hip/hip_runtime.h>
#include <hip/hip_bf16.h>

#define EMB 768
#define HEADS 12
#define DKV 64
#define BATCH 2
#define SEQ 2048
#define NTOK (BATCH*SEQ)   // 4096

typedef float f32x4 __attribute__((ext_vector_type(4)));
typedef unsigned short u16;
typedef u16 u16x8 __attribute__((ext_vector_type(8)));
typedef u16 u16x4 __attribute__((ext_vector_type(4)));
typedef __bf16 bf16x8 __attribute__((ext_vector_type(8)));

__device__ __forceinline__ u16 f2bf(float f) {
  return __builtin_bit_cast(u16, (__bf16)f);
}
__device__ __forceinline__ float fexp2(float x) {
#if __has_builtin(__builtin_amdgcn_exp2f)
  return __builtin_amdgcn_exp2f(x);
#else
  return exp2f(x);
#endif
}
__device__ __forceinline__ f32x4 mfma16(u16x8 a, u16x8 b, f32x4 c) {
  return __builtin_amdgcn_mfma_f32_16x16x32_bf16(
      __builtin_bit_cast(bf16x8, a), __builtin_bit_cast(bf16x8, b), c, 0, 0, 0);
}
// async global->LDS, 16B per lane; LDS dest = wave-uniform base + lane*16
__device__ __forceinline__ void gload16(const void* g, void* l) {
  __builtin_amdgcn_global_load_lds(
      (const __attribute__((address_space(1))) void*)g,
      (__attribute__((address_space(3))) void*)l, 16, 0, 0);
}

// ---------------- fused cast pass: 3 x's + 4 W's fp32 -> bf16 ----------------
// Wq gets scale csc (score scale folded into the Q projection weights).
__global__ void cast_all_k(
    const float* __restrict__ x0, const float* __restrict__ x1, const float* __restrict__ x2,
    const float* __restrict__ w0, const float* __restrict__ w1,
    const float* __restrict__ w2, const float* __restrict__ w3,
    u16* __restrict__ X0, u16* __restrict__ X1, u16* __restrict__ X2,
    u16* __restrict__ W0, u16* __restrict__ W1, u16* __restrict__ W2, u16* __restrict__ W3,
    float wscale0)
{
  const int NX = NTOK*EMB/8;   // 393216
  const int NW = EMB*EMB/8;    // 73728
  const int total = 3*NX + 4*NW;
  int i = blockIdx.x*256 + threadIdx.x;
  for (; i < total; i += gridDim.x*256) {
    const float* s; u16* d; int off; float sc = 1.f;
    if (i < 3*NX) {
      int which = i / NX; off = i - which*NX;
      s = which==0 ? x0 : which==1 ? x1 : x2;
      d = which==0 ? X0 : which==1 ? X1 : X2;
    } else {
      int j = i - 3*NX; int which = j / NW; off = j - which*NW;
      s = which==0 ? w0 : which==1 ? w1 : which==2 ? w2 : w3;
      d = which==0 ? W0 : which==1 ? W1 : which==2 ? W2 : W3;
      if (which == 0) sc = wscale0;
    }
    float4 a = reinterpret_cast<const float4*>(s)[off*2];
    float4 b = reinterpret_cast<const float4*>(s)[off*2+1];
    u16x8 o;
    o[0]=f2bf(a.x*sc); o[1]=f2bf(a.y*sc); o[2]=f2bf(a.z*sc); o[3]=f2bf(a.w*sc);
    o[4]=f2bf(b.x*sc); o[5]=f2bf(b.y*sc); o[6]=f2bf(b.z*sc); o[7]=f2bf(b.w*sc);
    reinterpret_cast<u16x8*>(d)[off] = o;
  }
}

// ---------------- GEMM core, m97 structure ----------------
// BM=BN=128, BK=64, 4 waves (2x2, each 64x64 out = 4x4 16x16 frags, 32 MFMA/step).
// Staging via global_load_lds w=16: LDS dest LINEAR, global source pre-swizzled
// sg = slot ^ (row&7) (rule #21: involution on both sides). Single-buffer LDS
// 32 KB, 2 barriers/step (m97's 874-TF-class schedule; compiler drains vmcnt
// before s_barrier). All inputs bf16 (cast pass).
// MODE 0: bf16 head-split [B][H][S][DKV] (+bias*bscale).
// MODE 1: fp32 [M][EMB] (+bias). MODE 2: bf16 head-split transposed [B][H][DKV][SEQ].
template<int MODE>
__device__ __forceinline__ void gemm_core(
    const u16* __restrict__ A, const u16* __restrict__ Bm,
    const float* __restrict__ bias, float bscale, void* __restrict__ outp,
    u16* __restrict__ At, u16* __restrict__ Bt, int m0, int n0)
{
  const int t = threadIdx.x;
  const int w = t >> 6, lane = t & 63, lg = lane >> 4, lr = lane & 15;
  const int wr = w >> 1, wc = w & 1;

  f32x4 acc[4][4] = {};

  // per wave: 4 A-chunks + 4 B-chunks of 1KB (8 rows x 8 slots x 16B), chunks w*4+i
  const int crow = (w*4)*8 + (lane >> 3);      // base row of this lane in chunk w*4
  const int csl  = lane & 7;                    // logical slot (= linear LDS slot)

  auto STAGE = [&](int kb) {
    #pragma unroll
    for (int i = 0; i < 4; ++i) {
      int row = crow + i*8;
      int sg = csl ^ (row & 7);                 // pre-swizzled source slot
      gload16(A  + (size_t)(m0+row)*EMB + kb + sg*8, &At[(w*4+i)*512]);
      gload16(Bm + (size_t)(n0+row)*EMB + kb + sg*8, &Bt[(w*4+i)*512]);
    }
  };

  auto COMPUTE = [&]() {
    u16x8 af[4][2], bf[4][2];
    #pragma unroll
    for (int fm = 0; fm < 4; ++fm)
      #pragma unroll
      for (int kk = 0; kk < 2; ++kk) {
        int r = wr*64 + fm*16 + lr;
        int p = (lg + 4*kk) ^ (r & 7);
        af[fm][kk] = *reinterpret_cast<const u16x8*>(&At[r*64 + p*8]);
      }
    #pragma unroll
    for (int fn = 0; fn < 4; ++fn)
      #pragma unroll
      for (int kk = 0; kk < 2; ++kk) {
        int r = wc*64 + fn*16 + lr;
        int p = (lg + 4*kk) ^ (r & 7);
        bf[fn][kk] = *reinterpret_cast<const u16x8*>(&Bt[r*64 + p*8]);
      }
    __builtin_amdgcn_s_setprio(1);
    #pragma unroll
    for (int fm = 0; fm < 4; ++fm)
      #pragma unroll
      for (int fn = 0; fn < 4; ++fn)
        #pragma unroll
        for (int kk = 0; kk < 2; ++kk)
          acc[fm][fn] = mfma16(af[fm][kk], bf[fn][kk], acc[fm][fn]);
    __builtin_amdgcn_s_setprio(0);
  };

  const int NSTEP = EMB/64;   // 12
  #pragma unroll
  for (int ts = 0; ts < NSTEP; ++ts) {
    STAGE(ts*64);
    __syncthreads();            // vmcnt(0) drained -> tile visible
    COMPUTE();
    if (ts+1 < NSTEP) __syncthreads();   // readers done before overwrite
  }

  // epilogue: C layout col = lane&15, row = (lane>>4)*4 + j  [measured m89]
  #pragma unroll
  for (int fm = 0; fm < 4; ++fm)
    #pragma unroll
    for (int fn = 0; fn < 4; ++fn) {
      const int mb = m0 + wr*64 + fm*16 + lg*4;
      const int e  = n0 + wc*64 + fn*16 + lr;
      if constexpr (MODE == 2) {
        int bb = mb >> 11, sb = mb & 2047, h = e >> 6, d = e & 63;
        u16x4 o4;
        #pragma unroll
        for (int j = 0; j < 4; ++j) o4[j] = f2bf(acc[fm][fn][j] + bias[e]*bscale);
        *reinterpret_cast<u16x4*>(
            reinterpret_cast<u16*>(outp) + (((size_t)(bb*HEADS+h))*DKV + d)*SEQ + sb) = o4;
      } else {
        #pragma unroll
        for (int j = 0; j < 4; ++j) {
          int m = mb + j;
          float val = acc[fm][fn][j] + bias[e]*bscale;
          if constexpr (MODE == 0) {
            int bb = m >> 11, s = m & 2047, h = e >> 6, d = e & 63;
            reinterpret_cast<u16*>(outp)[(((size_t)(bb*HEADS+h))*SEQ + s)*DKV + d] = f2bf(val);
          } else {
            reinterpret_cast<float*>(outp)[(size_t)m*EMB + e] = val;
          }
        }
      }
    }
}

// fused Q/K/V projections: blockIdx.z selects which (all inputs bf16)
__global__ __launch_bounds__(256) void qkv_k(
    const u16* __restrict__ Xq, const u16* __restrict__ Xk, const u16* __restrict__ Xv,
    const u16* __restrict__ Wq, const u16* __restrict__ Wk, const u16* __restrict__ Wv,
    const float* __restrict__ bq, const float* __restrict__ bk, const float* __restrict__ bv,
    u16* __restrict__ Qh, u16* __restrict__ Kh, u16* __restrict__ Vh, float csc)
{
  __shared__ __align__(16) u16 At[128*64];
  __shared__ __align__(16) u16 Bt[128*64];
  const int m0 = blockIdx.x*128, n0 = blockIdx.y*128;
  const int z = blockIdx.z;
  if (z == 0)
    gemm_core<0>(Xq, Wq, bq, csc, Qh, At, Bt, m0, n0);
  else if (z == 1)
    gemm_core<0>(Xk, Wk, bk, 1.f, Kh, At, Bt, m0, n0);
  else
    gemm_core<2>(Xv, Wv, bv, 1.f, Vh, At, Bt, m0, n0);
}

// output projection (A = attn output, already bf16)
__global__ __launch_bounds__(256) void gemm_out_k(
    const u16* __restrict__ A, const u16* __restrict__ Bm,
    const float* __restrict__ bias, float* __restrict__ outp)
{
  __shared__ __align__(16) u16 At[128*64];
  __shared__ __align__(16) u16 Bt[128*64];
  gemm_core<1>(A, Bm, bias, 1.f, outp, At, Bt, blockIdx.x*128, blockIdx.y*128);
}

// ---------------- flash attention: 2-tile pipeline (unchanged from round 8) ----------------
__global__ __launch_bounds__(256) void flash_attn_k(
    const u16* __restrict__ Q, const u16* __restrict__ K, const u16* __restrict__ VT,
    u16* __restrict__ av)
{
  __shared__ __align__(16) u16 Kt[2][64*64];     // [key][d] swizzled
  __shared__ __align__(16) u16 Vt[2][64*64];     // [d][key] swizzled
  __shared__ __align__(16) u16 Pt[4][2][16*64];  // per-wave, double-buffered

  const int t = threadIdx.x;
  const int w = t >> 6, lane = t & 63, lg = lane >> 4, lr = lane & 15;
  const int tr = t >> 3, tsl = t & 7;
  const int qb = blockIdx.x;       // 0..31
  const int bh = blockIdx.y;       // 0..23
  const u16* Qb = Q  + (size_t)bh*SEQ*DKV;
  const u16* Kb = K  + (size_t)bh*SEQ*DKV;
  const u16* Vb = VT + (size_t)bh*DKV*SEQ;

  const int qrow = qb*64 + w*16 + lr;
  u16x8 qf[2];
  qf[0] = *reinterpret_cast<const u16x8*>(Qb + (size_t)qrow*DKV + lg*8);
  qf[1] = *reinterpret_cast<const u16x8*>(Qb + (size_t)qrow*DKV + 32 + lg*8);

  f32x4 acc[4] = {};   // O^T: acc[fc][j] -> d = fc*16+lg*4+j, q = lr
  float mrun = -1e30f, lrun = 0.f;   // lrun = per-lane PARTIAL (16 keys/tile)
  f32x4 s[4];

  u16x8 ks[2], vs[2];
  auto LOADKV = [&](int kt0) {
    #pragma unroll
    for (int q = 0; q < 2; ++q) {
      int row = q*32 + tr;
      ks[q] = *reinterpret_cast<const u16x8*>(Kb + (size_t)(kt0+row)*DKV + tsl*8);
    }
    #pragma unroll
    for (int q = 0; q < 2; ++q) {
      int d = q*32 + tr;
      vs[q] = *reinterpret_cast<const u16x8*>(Vb + (size_t)d*SEQ + kt0 + tsl*8);
    }
  };

  const int NT = SEQ/64;   // 32

#define WKV(bi)                                                               \
  do {                                                                        \
    _Pragma("unroll")                                                         \
    for (int q = 0; q < 2; ++q) {                                             \
      int row = q*32 + tr;                                                    \
      *reinterpret_cast<u16x8*>(&Kt[bi][row*64 + ((tsl ^ (row & 7))*8)]) = ks[q]; \
    }                                                                         \
    _Pragma("unroll")                                                         \
    for (int q = 0; q < 2; ++q) {                                             \
      int d = q*32 + tr;                                                      \
      *reinterpret_cast<u16x8*>(&Vt[bi][d*64 + ((tsl ^ (d & 7))*8)]) = vs[q]; \
    }                                                                         \
  } while (0)

#define QK_MFMA(bi)                                                           \
  do {                                                                        \
    _Pragma("unroll")                                                         \
    for (int fc = 0; fc < 4; ++fc) {                                          \
      f32x4 z = {};                                                           \
      _Pragma("unroll")                                                       \
      for (int kk = 0; kk < 2; ++kk) {                                        \
        int r = fc*16 + lr;                                                   \
        int slot = (lg + 4*kk) ^ (r & 7);                                     \
        u16x8 kf = *reinterpret_cast<const u16x8*>(&Kt[bi][r*64 + slot*8]);   \
        z = mfma16(kf, qf[kk], z);                                            \
      }                                                                       \
      s[fc] = z;                                                              \
    }                                                                         \
  } while (0)

#define PV_MFMA(bi)                                                           \
  do {                                                                        \
    const char* Pr = reinterpret_cast<const char*>(&Pt[w][bi][0]);            \
    _Pragma("unroll")                                                         \
    for (int kk = 0; kk < 2; ++kk) {                                          \
      u16x8 pf = *reinterpret_cast<const u16x8*>(                             \
          Pr + lr*128 + (((kk*8 + lg*2) ^ ((lr & 7) << 1))*8));               \
      _Pragma("unroll")                                                       \
      for (int fc = 0; fc < 4; ++fc) {                                        \
        int rv = fc*16 + lr;                                                  \
        int slotv = (lg + 4*kk) ^ (rv & 7);                                   \
        u16x8 vf = *reinterpret_cast<const u16x8*>(&Vt[bi][rv*64 + slotv*8]); \
        acc[fc] = mfma16(vf, pf, acc[fc]);                                    \
      }                                                                       \
    }                                                                         \
  } while (0)

#define SOFTMAX_PW(bi)                                                        \
  do {                                                                        \
    float a0 = fmaxf(fmaxf(s[0][0], s[0][1]), s[0][2]);                       \
    float a1 = fmaxf(fmaxf(s[0][3], s[1][0]), s[1][1]);                       \
    float a2 = fmaxf(fmaxf(s[1][2], s[1][3]), s[2][0]);                       \
    float a3 = fmaxf(fmaxf(s[2][1], s[2][2]), s[2][3]);                       \
    float a4 = fmaxf(fmaxf(s[3][0], s[3][1]), s[3][2]);                       \
    float pmax = fmaxf(fmaxf(fmaxf(a0, a1), a2),                              \
                       fmaxf(fmaxf(a3, a4), s[3][3]));                        \
    if (__any(pmax > mrun + 8.f)) {   /* rare: full reduce + rescale */       \
      float pm = fmaxf(pmax, __shfl_xor(pmax, 16));                           \
      pm = fmaxf(pm, __shfl_xor(pm, 32));                                     \
      float mnew = fmaxf(mrun, pm);                                           \
      float corr = fexp2(mrun - mnew);                                        \
      mrun = mnew; lrun *= corr;                                              \
      _Pragma("unroll")                                                       \
      for (int fc = 0; fc < 4; ++fc)                                          \
        _Pragma("unroll")                                                     \
        for (int j = 0; j < 4; ++j)                                           \
          acc[fc][j] *= corr;                                                 \
    }                                                                         \
    float p[4][4], rsv[4];                                                    \
    _Pragma("unroll")                                                         \
    for (int fc = 0; fc < 4; ++fc) {                                          \
      _Pragma("unroll")                                                       \
      for (int j = 0; j < 4; ++j) p[fc][j] = fexp2(s[fc][j] - mrun);          \
      rsv[fc] = (p[fc][0] + p[fc][1]) + (p[fc][2] + p[fc][3]);                \
    }                                                                         \
    lrun += (rsv[0] + rsv[1]) + (rsv[2] + rsv[3]);                            \
    char* Pw_ = reinterpret_cast<char*>(&Pt[w][bi][0]);                       \
    _Pragma("unroll")                                                         \
    for (int fc = 0; fc < 4; ++fc) {                                          \
      u16x4 q4;                                                               \
      _Pragma("unroll")                                                       \
      for (int j = 0; j < 4; ++j) q4[j] = f2bf(p[fc][j]);                     \
      *reinterpret_cast<u16x4*>(                                              \
          Pw_ + lr*128 + (((fc*4 + lg) ^ ((lr & 7) << 1))*8)) = q4;           \
    }                                                                         \
  } while (0)

#define ITER(bi, kt)                                                          \
  do {                                                                        \
    __builtin_amdgcn_s_setprio(1);                                            \
    QK_MFMA(bi);                                                              \
    PV_MFMA(bi^1);                                                            \
    __builtin_amdgcn_s_setprio(0);                                            \
    SOFTMAX_PW(bi);                                                           \
    __syncthreads();                  /* all waves done reading V(t-1) */     \
    if ((kt)+1 < NT) WKV(bi^1);       /* overwrite K/V(t-1) slot */           \
    __syncthreads();                  /* K/V(t+1) visible */                  \
    if ((kt)+2 < NT) LOADKV(((kt)+2)*64);                                     \
  } while (0)

  // prologue: tile 0 has no PV predecessor
  LOADKV(0);
  WKV(0);
  __syncthreads();
  LOADKV(64);
  QK_MFMA(0);
  SOFTMAX_PW(0);
  WKV(1);
  __syncthreads();
  LOADKV(128);

  for (int kt = 1; kt+1 < NT; kt += 2) {
    ITER(1, kt);
    ITER(0, kt+1);
  }
  ITER(1, NT-1);     // NT-1 = 31 odd

  // epilogue: drain PV(NT-1), reduce partial lrun, normalize, store
  PV_MFMA(1);
  float lt = lrun;
  lt += __shfl_xor(lt, 16);
  lt += __shfl_xor(lt, 32);
  const float inv = 1.0f / lt;

  const int b = bh / HEADS, h = bh % HEADS;
  #pragma unroll
  for (int fc = 0; fc < 4; ++fc) {
    u16x4 o4;
    #pragma unroll
    for (int j = 0; j < 4; ++j) o4[j] = f2bf(acc[fc][j] * inv);
    *reinterpret_cast<u16x4*>(
        av + ((size_t)(b*SEQ + qrow))*EMB + h*64 + fc*16 + lg*4) = o4;
  }
#undef ITER
#undef SOFTMAX_PW
#undef PV_MFMA
#undef QK_MFMA
#undef WKV
}

// ---------------- launcher: 4 kernels ----------------
extern "C" void kernel_launch(void* const* d_in, const int* in_sizes, int n_in,
                              void* d_out, int out_size, void* d_ws, size_t ws_size,
                              hipStream_t stream) {
  const float* xq_f = (const float*)d_in[0];
  const float* xk_f = (const float*)d_in[1];
  const float* xv_f = (const float*)d_in[2];
  const float* Wq = (const float*)d_in[3];
  const float* bq = (const float*)d_in[4];
  const float* Wk = (const float*)d_in[5];
  const float* bk = (const float*)d_in[6];
  const float* Wv = (const float*)d_in[7];
  const float* bv = (const float*)d_in[8];
  const float* Wo = (const float*)d_in[9];
  const float* bo = (const float*)d_in[10];

  const size_t NX = (size_t)NTOK*EMB;    // 3145728 elems
  const size_t NW = (size_t)EMB*EMB;     // 589824 elems
  u16* Xc0 = (u16*)d_ws;                 // bf16 query input
  u16* Xc1 = Xc0 + NX;
  u16* Xc2 = Xc1 + NX;
  u16* Wc0 = Xc2 + NX;                   // bf16 Wq (pre-scaled by csc)
  u16* Wc1 = Wc0 + NW;
  u16* Wc2 = Wc1 + NW;
  u16* Wc3 = Wc2 + NW;
  u16* Qh  = Wc3 + NW;                   // [B][H][S][DKV]
  u16* Kh  = Qh + NX;
  u16* Vh  = Kh + NX;                    // [B][H][DKV][SEQ] (V^T)
  u16* Xb  = Xc0;                        // attn out aliases Xc (dead after qkv)

  const float csc = 0.125f * 1.4426950408889634f;  // score scale -> Wq/bq

  cast_all_k<<<dim3(2048), dim3(256), 0, stream>>>(
      xq_f, xk_f, xv_f, Wq, Wk, Wv, Wo,
      Xc0, Xc1, Xc2, Wc0, Wc1, Wc2, Wc3, csc);

  qkv_k<<<dim3(NTOK/128, EMB/128, 3), dim3(256), 0, stream>>>(
      Xc0, Xc1, Xc2, Wc0, Wc1, Wc2, bq, bk, bv, Qh, Kh, Vh, csc);

  flash_attn_k<<<dim3(SEQ/64, BATCH*HEADS), dim3(256), 0, stream>>>(Qh, Kh, Vh, Xb);

  gemm_out_k<<<dim3(NTOK/128, EMB/128), dim3(256), 0, stream>>>(Xb, Wc3, bo, (float*)d_out);
}